// Round 1
// baseline (651.982 us; speedup 1.0000x reference)
//
#include <hip/hip_runtime.h>

typedef unsigned short u16;
typedef short short8 __attribute__((ext_vector_type(8)));
typedef float floatx4 __attribute__((ext_vector_type(4)));

#define TOKENS 8192
#define DIN    2048
#define DOUT   8192
#define NELEM  (DOUT * DIN)   // 16,777,216 — same count for input (8192x2048)

// ---------------- helpers ----------------

__device__ __forceinline__ u16 f2bf(float f) {
    // round-to-nearest-even f32 -> bf16 (no NaN in this data)
    unsigned u = __float_as_uint(f);
    unsigned r = (u + 0x7FFFu + ((u >> 16) & 1u)) >> 16;
    return (u16)r;
}

__device__ __forceinline__ void gld16(const void* src, void* lds) {
    // async global->LDS, 16B per lane; LDS dest is wave-uniform base + lane*16
    __builtin_amdgcn_global_load_lds((__attribute__((address_space(1))) void*)src,
                                     (__attribute__((address_space(3))) void*)lds,
                                     16, 0, 0);
}

// ---------------- conversion kernels ----------------

__global__ __launch_bounds__(256) void cvt_input_k(const float4* __restrict__ in,
                                                   ushort4* __restrict__ out, int n4) {
    int idx = blockIdx.x * 256 + threadIdx.x;
    int stride = gridDim.x * 256;
    for (int i = idx; i < n4; i += stride) {
        float4 v = in[i];
        ushort4 r;
        r.x = f2bf(v.x); r.y = f2bf(v.y); r.z = f2bf(v.z); r.w = f2bf(v.w);
        out[i] = r;
    }
}

__device__ __forceinline__ u16 sgnbf(float v) {
    return (v > 0.f) ? (u16)0x3F80 : ((v < 0.f) ? (u16)0xBF80 : (u16)0);
}

__global__ __launch_bounds__(256) void cvt_weight_k(const float4* __restrict__ w,
                                                    ushort4* __restrict__ out,
                                                    double* __restrict__ sacc, int n4) {
    int idx = blockIdx.x * 256 + threadIdx.x;
    int stride = gridDim.x * 256;
    float s = 0.f;
    for (int i = idx; i < n4; i += stride) {
        float4 v = w[i];
        ushort4 r;
        r.x = sgnbf(v.x); r.y = sgnbf(v.y); r.z = sgnbf(v.z); r.w = sgnbf(v.w);
        out[i] = r;
        s += fabsf(v.x) + fabsf(v.y) + fabsf(v.z) + fabsf(v.w);
    }
    // wave reduce (64 lanes)
    for (int off = 32; off > 0; off >>= 1) s += __shfl_down(s, off);
    __shared__ float red[4];
    int lane = threadIdx.x & 63, wave = threadIdx.x >> 6;
    if (lane == 0) red[wave] = s;
    __syncthreads();
    if (threadIdx.x == 0)
        atomicAdd(sacc, (double)(red[0] + red[1] + red[2] + red[3]));
}

// ---------------- GEMM: out[t,o] = scale * sum_k A[t,k]*sgn[o,k] + bias[o] -------------
// 128x128 tile, BK=32, 4 waves in 2x2 (each wave 64x64 = 4x4 frags of 16x16x32 bf16 MFMA)

__global__ __launch_bounds__(256) void bitgemm_k(const u16* __restrict__ A,
                                                 const u16* __restrict__ B,
                                                 const float* __restrict__ bias,
                                                 const double* __restrict__ sacc,
                                                 float* __restrict__ C) {
    __shared__ __align__(16) u16 As[128 * 32];
    __shared__ __align__(16) u16 Bs[128 * 32];

    const int tid  = threadIdx.x;
    const int lane = tid & 63;
    const int wave = tid >> 6;
    const int m0 = blockIdx.y * 128;   // token tile
    const int n0 = blockIdx.x * 128;   // output-feature tile
    const int wm = (wave >> 1) * 64;
    const int wn = (wave & 1) * 64;

    floatx4 acc[4][4];
    floatx4 z = {0.f, 0.f, 0.f, 0.f};
    for (int m = 0; m < 4; ++m)
        for (int n = 0; n < 4; ++n) acc[m][n] = z;

    // staging geometry: tile is 128 rows x 32 k (64B/row = 4 chunks of 16B)
    // chunk c (0..511): row = c>>2, k-offset = (c&3)*8; call j covers chunks j*256..j*256+255
    const int c0 = tid,        r0 = c0 >> 2, kof0 = (c0 & 3) << 3;
    const int c1 = 256 + tid,  r1 = c1 >> 2, kof1 = (c1 & 3) << 3;

    const u16* a0 = A + (size_t)(m0 + r0) * DIN + kof0;
    const u16* a1 = A + (size_t)(m0 + r1) * DIN + kof1;
    const u16* b0 = B + (size_t)(n0 + r0) * DIN + kof0;
    const u16* b1 = B + (size_t)(n0 + r1) * DIN + kof1;

    // wave-uniform LDS bases (lane*16B applied by HW)
    u16* ldsA0 = As + (wave * 64) * 8;
    u16* ldsA1 = As + (256 + wave * 64) * 8;
    u16* ldsB0 = Bs + (wave * 64) * 8;
    u16* ldsB1 = Bs + (256 + wave * 64) * 8;

    // fragment read addresses: row = (wm|wn) + m*16 + (lane&15), k = (lane>>4)*8
    const int frow = lane & 15;
    const int kgrp = (lane >> 4) * 8;
    const u16* aBase = As + (wm + frow) * 32 + kgrp;
    const u16* bBase = Bs + (wn + frow) * 32 + kgrp;

    for (int k0 = 0; k0 < DIN; k0 += 32) {
        gld16(a0 + k0, ldsA0);
        gld16(a1 + k0, ldsA1);
        gld16(b0 + k0, ldsB0);
        gld16(b1 + k0, ldsB1);
        __syncthreads();   // compiler emits vmcnt(0) drain before s_barrier

        short8 af[4], bf[4];
        for (int m = 0; m < 4; ++m) af[m] = *(const short8*)(aBase + m * 16 * 32);
        for (int n = 0; n < 4; ++n) bf[n] = *(const short8*)(bBase + n * 16 * 32);
        for (int m = 0; m < 4; ++m)
            for (int n = 0; n < 4; ++n)
                acc[m][n] = __builtin_amdgcn_mfma_f32_16x16x32_bf16(af[m], bf[n], acc[m][n], 0, 0, 0);
        __syncthreads();
    }

    // epilogue: C[t,o] = acc*scale + bias[o]
    const float scale = (float)(sacc[0] * (1.0 / (double)NELEM));
    const int rowb = (lane >> 4) * 4;   // D row = (lane>>4)*4 + reg
    const int colb = lane & 15;         // D col = lane&15
    for (int n = 0; n < 4; ++n) {
        const int o = n0 + wn + n * 16 + colb;
        const float bo = bias[o];
        for (int m = 0; m < 4; ++m) {
            const int t = m0 + wm + m * 16 + rowb;
            floatx4 v = acc[m][n];
            for (int r = 0; r < 4; ++r)
                C[(size_t)(t + r) * DOUT + o] = v[r] * scale + bo;
        }
    }
}

// ---------------- launch ----------------

extern "C" void kernel_launch(void* const* d_in, const int* in_sizes, int n_in,
                              void* d_out, int out_size, void* d_ws, size_t ws_size,
                              hipStream_t stream) {
    const float* inp  = (const float*)d_in[0];   // [8192, 2048]
    const float* wgt  = (const float*)d_in[1];   // [8192, 2048]
    const float* bias = (const float*)d_in[2];   // [8192]
    float* out = (float*)d_out;                  // [8192, 8192]

    u16* Abf = (u16*)d_ws;            // 32 MB bf16 input
    u16* Bbf = Abf + NELEM;           // 32 MB bf16 sign(W)
    double* sacc = (double*)(Bbf + NELEM);  // 8 B |W| sum

    hipMemsetAsync(sacc, 0, sizeof(double), stream);
    cvt_weight_k<<<2048, 256, 0, stream>>>((const float4*)wgt, (ushort4*)Bbf, sacc, NELEM / 4);
    cvt_input_k<<<2048, 256, 0, stream>>>((const float4*)inp, (ushort4*)Abf, NELEM / 4);

    dim3 grid(DOUT / 128, TOKENS / 128);
    bitgemm_k<<<grid, 256, 0, stream>>>(Abf, Bbf, bias, sacc, out);
}

// Round 3
// 597.536 us; speedup vs baseline: 1.0911x; 1.0911x over previous
//
#include <hip/hip_runtime.h>

typedef unsigned short u16;
typedef short short8 __attribute__((ext_vector_type(8)));
typedef float floatx4 __attribute__((ext_vector_type(4)));

#define TOKENS 8192
#define DIN    2048
#define DOUT   8192
#define NELEM  (DOUT * DIN)

#define BM 256
#define BN 256
#define BK 32
#define NT (DIN / BK)     // 64 K-tiles
#define NBUF 3            // triple buffer: LDS = 3 * (16KB A + 16KB B) = 96KB

// ---------------- helpers ----------------

__device__ __forceinline__ u16 f2bf(float f) {
    unsigned u = __float_as_uint(f);
    unsigned r = (u + 0x7FFFu + ((u >> 16) & 1u)) >> 16;
    return (u16)r;
}

__device__ __forceinline__ void gld16(const void* src, void* ldsp) {
    __builtin_amdgcn_global_load_lds((__attribute__((address_space(1))) void*)src,
                                     (__attribute__((address_space(3))) void*)ldsp,
                                     16, 0, 0);
}

// ---------------- conversion kernels (no contended atomics) ----------------

__global__ __launch_bounds__(256) void cvt_input_k(const float4* __restrict__ in,
                                                   ushort4* __restrict__ out, int n4) {
    int idx = blockIdx.x * 256 + threadIdx.x;
    int stride = gridDim.x * 256;
    for (int i = idx; i < n4; i += stride) {
        float4 v = in[i];
        ushort4 r;
        r.x = f2bf(v.x); r.y = f2bf(v.y); r.z = f2bf(v.z); r.w = f2bf(v.w);
        out[i] = r;
    }
}

__device__ __forceinline__ u16 sgnbf(float v) {
    return (v > 0.f) ? (u16)0x3F80 : ((v < 0.f) ? (u16)0xBF80 : (u16)0);
}

__global__ __launch_bounds__(256) void cvt_weight_k(const float4* __restrict__ w,
                                                    ushort4* __restrict__ out,
                                                    float* __restrict__ part, int n4) {
    int idx = blockIdx.x * 256 + threadIdx.x;
    int stride = gridDim.x * 256;
    float s = 0.f;
    for (int i = idx; i < n4; i += stride) {
        float4 v = w[i];
        ushort4 r;
        r.x = sgnbf(v.x); r.y = sgnbf(v.y); r.z = sgnbf(v.z); r.w = sgnbf(v.w);
        out[i] = r;
        s += fabsf(v.x) + fabsf(v.y) + fabsf(v.z) + fabsf(v.w);
    }
    for (int off = 32; off > 0; off >>= 1) s += __shfl_down(s, off);
    __shared__ float red[4];
    int lane = threadIdx.x & 63, wave = threadIdx.x >> 6;
    if (lane == 0) red[wave] = s;
    __syncthreads();
    if (threadIdx.x == 0) part[blockIdx.x] = red[0] + red[1] + red[2] + red[3];
}

__global__ __launch_bounds__(256) void reduce_scale_k(const float* __restrict__ part,
                                                      float* __restrict__ scalep, int n) {
    double s = 0.0;
    for (int i = threadIdx.x; i < n; i += 256) s += (double)part[i];
    for (int off = 32; off > 0; off >>= 1) s += __shfl_down(s, off);
    __shared__ double red[4];
    int lane = threadIdx.x & 63, wave = threadIdx.x >> 6;
    if (lane == 0) red[wave] = s;
    __syncthreads();
    if (threadIdx.x == 0)
        scalep[0] = (float)((red[0] + red[1] + red[2] + red[3]) / (double)NELEM);
}

// ---------------- GEMM ----------------
// 256x256 tile, BK=32, 8 waves (2M x 4N), wave tile 128x64 (acc[8][4] of 16x16 frags).
// Triple-buffered LDS, counted vmcnt(4) (never 0 in steady state), raw s_barrier,
// XOR-swizzled LDS (pair-row view [128 rows][8 x 16B slots], slot ^= pairrow&7),
// inverse swizzle applied on per-lane GLOBAL source (global_load_lds dest is linear).

__global__ __launch_bounds__(512, 2) void bitgemm_k(const u16* __restrict__ A,
                                                    const u16* __restrict__ B,
                                                    const float* __restrict__ bias,
                                                    const float* __restrict__ scalep,
                                                    float* __restrict__ C) {
    // per buffer: A tile 256x32 bf16 = 16384 B at +0, B tile at +16384
    __shared__ __align__(16) char lds[NBUF * 32768];

    const int tid  = threadIdx.x;
    const int lane = tid & 63;
    const int wave = tid >> 6;

    // XCD-bijective swizzle: nwg = 32*32 = 1024, divisible by 8
    const int flat = blockIdx.y * gridDim.x + blockIdx.x;
    const int cpx  = (gridDim.x * gridDim.y) >> 3;
    const int swz  = (flat & 7) * cpx + (flat >> 3);
    const int m0 = (swz >> 5) * BM;    // 32 tiles per row
    const int n0 = (swz & 31) * BN;

    const int wm = (wave >> 2) * 128;  // wave M offset (2 groups)
    const int wn = (wave & 3) * 64;    // wave N offset (4 groups)

    // ---- staging source addresses (swizzle-inverted global src, linear LDS dest) ----
    // chunk c covers LDS bytes [c*8192 + tid*16): pairrow p = lin>>7, slot s' = (lin>>4)&7
    // stored granule (row, g): s = s' ^ (p&7), row = 2p + (s>>2), g = s&3
    const u16* srcA[2];
    const u16* srcB[2];
#pragma unroll
    for (int c = 0; c < 2; ++c) {
        int lin = c * 8192 + tid * 16;
        int p   = lin >> 7;
        int sp  = (lin >> 4) & 7;
        int s   = sp ^ (p & 7);
        int row = 2 * p + (s >> 2);
        int g   = s & 3;
        srcA[c] = A + (size_t)(m0 + row) * DIN + g * 8;
        srcB[c] = B + (size_t)(n0 + row) * DIN + g * 8;
    }

#define STAGE(kt, sb) do {                                                   \
        char* base_ = lds + (sb) * 32768;                                    \
        gld16(srcA[0] + (kt) * BK, base_ +         wave * 1024);             \
        gld16(srcA[1] + (kt) * BK, base_ +  8192 + wave * 1024);             \
        gld16(srcB[0] + (kt) * BK, base_ + 16384 + wave * 1024);             \
        gld16(srcB[1] + (kt) * BK, base_ + 24576 + wave * 1024);             \
    } while (0)

    // ---- fragment read offsets (swizzled) ----
    // frag row = (wm|wn) + i*16 + (lane&15), granule g = lane>>4
    // byte = p*128 + (((row&1)*4+g) ^ (p&7))*16, p = row>>1; +i*16 rows => +i*1024 bytes
    const int gg = lane >> 4;
    const int rA = wm + (lane & 15);
    const int pA = rA >> 1;
    const int offA = pA * 128 + ((((rA & 1) << 2) | gg) ^ (pA & 7)) * 16;
    const int rB = wn + (lane & 15);
    const int pB = rB >> 1;
    const int offB = 16384 + pB * 128 + ((((rB & 1) << 2) | gg) ^ (pB & 7)) * 16;

    floatx4 acc[8][4];
    floatx4 z = {0.f, 0.f, 0.f, 0.f};
#pragma unroll
    for (int m = 0; m < 8; ++m)
#pragma unroll
        for (int n = 0; n < 4; ++n) acc[m][n] = z;

    // ---- prologue: tiles 0,1 in flight; wait tile 0 (4 newest = tile 1 stay in flight) ----
    STAGE(0, 0);
    STAGE(1, 1);
    asm volatile("s_waitcnt vmcnt(4)" ::: "memory");
    __builtin_amdgcn_s_barrier();
    __builtin_amdgcn_sched_barrier(0);

    for (int t = 0; t < NT; ++t) {
        // issue next+1 tile into the buffer freed at the end of iteration t-1
        if (t + 2 < NT) STAGE(t + 2, (t + 2) % 3);

        const char* bufA = lds + (t % 3) * 32768 + offA;
        const char* bufB = lds + (t % 3) * 32768 + offB;
        short8 af[8], bq[4];
#pragma unroll
        for (int m = 0; m < 8; ++m) af[m] = *(const short8*)(bufA + m * 1024);
#pragma unroll
        for (int n = 0; n < 4; ++n) bq[n] = *(const short8*)(bufB + n * 1024);

        __builtin_amdgcn_s_setprio(1);
#pragma unroll
        for (int m = 0; m < 8; ++m)
#pragma unroll
            for (int n = 0; n < 4; ++n)
                acc[m][n] = __builtin_amdgcn_mfma_f32_16x16x32_bf16(af[m], bq[n], acc[m][n], 0, 0, 0);
        __builtin_amdgcn_s_setprio(0);

        if (t + 1 < NT) {
            // own tile-(t+1) loads are older than the 4 tile-(t+2) loads just issued
            if (t + 2 < NT) asm volatile("s_waitcnt vmcnt(4)" ::: "memory");
            else            asm volatile("s_waitcnt vmcnt(0)" ::: "memory");
            __builtin_amdgcn_s_barrier();
            __builtin_amdgcn_sched_barrier(0);
        }
    }
#undef STAGE

    // ---- epilogue: C = acc*scale + bias ----
    const float scale = scalep[0];
    const int rowe = (lane >> 4) * 4;   // D row = (lane>>4)*4 + reg
    const int cole = lane & 15;         // D col = lane&15
#pragma unroll
    for (int n = 0; n < 4; ++n) {
        const int o = n0 + wn + n * 16 + cole;
        const float bo = bias[o];
#pragma unroll
        for (int m = 0; m < 8; ++m) {
            const int trow = m0 + wm + m * 16 + rowe;
            floatx4 v = acc[m][n];
#pragma unroll
            for (int r = 0; r < 4; ++r)
                C[(size_t)(trow + r) * DOUT + o] = v[r] * scale + bo;
        }
    }
}

// ---------------- launch ----------------

extern "C" void kernel_launch(void* const* d_in, const int* in_sizes, int n_in,
                              void* d_out, int out_size, void* d_ws, size_t ws_size,
                              hipStream_t stream) {
    const float* inp  = (const float*)d_in[0];   // [8192, 2048]
    const float* wgt  = (const float*)d_in[1];   // [8192, 2048]
    const float* bias = (const float*)d_in[2];   // [8192]
    float* out = (float*)d_out;                  // [8192, 8192]

    u16* Abf = (u16*)d_ws;                 // 32 MB bf16 input
    u16* Bbf = Abf + NELEM;                // 32 MB bf16 sign(W)
    float* part   = (float*)(Bbf + NELEM); // 1024 block partials
    float* scalep = part + 1024;           // scalar scale

    cvt_weight_k<<<1024, 256, 0, stream>>>((const float4*)wgt, (ushort4*)Bbf, part, NELEM / 4);
    cvt_input_k<<<1024, 256, 0, stream>>>((const float4*)inp, (ushort4*)Abf, NELEM / 4);
    reduce_scale_k<<<1, 256, 0, stream>>>(part, scalep, 1024);

    dim3 grid(DOUT / BN, TOKENS / BM);     // 32 x 32
    bitgemm_k<<<grid, 512, 0, stream>>>(Abf, Bbf, bias, scalep, out);
}